// Round 5
// baseline (395.003 us; speedup 1.0000x reference)
//
#include <hip/hip_runtime.h>
#include <hip/hip_bf16.h>

#define DIM 128
#define KCODES 1024
#define BROWS 128        // rows per block (4 waves x 32 rows)
#define TAU 2e-3f

typedef __attribute__((ext_vector_type(8))) short bf16x8;
typedef __attribute__((ext_vector_type(4))) float f32x4;

__device__ __forceinline__ unsigned short f2bf(float x, float* back) {
    __hip_bfloat16 h = __float2bfloat16(x);   // RNE
    *back = __bfloat162float(h);
    union { __hip_bfloat16 hh; unsigned short u; } cv; cv.hh = h;
    return cv.u;
}

// ---------- prep: E -> bf16 hi/lo (linear layout) + ||e||^2, fused ----------
// one thread per (code, 8-elem segment): t = k*16 + s. 16-lane groups = one code.
__global__ void pack_kernel(const float* __restrict__ embed, unsigned short* __restrict__ Ehi,
                            unsigned short* __restrict__ Elo, float* __restrict__ enorm) {
    int t = blockIdx.x * blockDim.x + threadIdx.x;   // 0 .. KCODES*16-1
    int k = t >> 4;
    int s = t & 15;
    const float* src = embed + (size_t)k * DIM + s * 8;
    float4 a0 = *(const float4*)src;
    float4 a1 = *(const float4*)(src + 4);
    float f[8] = {a0.x, a0.y, a0.z, a0.w, a1.x, a1.y, a1.z, a1.w};
    bf16x8 h8, l8;
    float ps = 0.f;
#pragma unroll
    for (int j = 0; j < 8; ++j) {
        float bk, dd;
        h8[j] = (short)f2bf(f[j], &bk);
        l8[j] = (short)f2bf(f[j] - bk, &dd);
        ps = fmaf(f[j], f[j], ps);
    }
    *(bf16x8*)&Ehi[(size_t)k * DIM + s * 8] = h8;
    *(bf16x8*)&Elo[(size_t)k * DIM + s * 8] = l8;
    // reduce ||e||^2 over the 16 lanes of this code
#pragma unroll
    for (int mask = 1; mask < 16; mask <<= 1) ps += __shfl_xor(ps, mask);
    if (s == 0) enorm[k] = ps;
}

// ---------- main: barrier-free B-streaming MFMA argmax + top-2 refine + fused gather ----------
__global__ __launch_bounds__(256, 2)
void argmax_mfma_kernel(const float* __restrict__ x, const float* __restrict__ embed,
                        const unsigned short* __restrict__ Ehi, const unsigned short* __restrict__ Elo,
                        const float* __restrict__ enorm,
                        float* __restrict__ outq, float* __restrict__ outi) {
    __shared__ int idx_l[BROWS];
    __shared__ int flist[BROWS];
    __shared__ int fcnt;

    const int tid = threadIdx.x;
    const int w = tid >> 6;          // wave id 0..3
    const int lane = tid & 63;
    const int n = lane & 15;         // code class / A-row class
    const int q = lane >> 4;         // k-segment (A/B) / row group (C)
    const size_t row0 = (size_t)blockIdx.x * BROWS;

    if (tid == 0) fcnt = 0;
    __syncthreads();                 // make fcnt=0 visible before any atomicAdd (loop is barrier-free)

    // A fragments: wave's 32 rows, bf16 hi/lo, resident in registers.
    // layout: A[m=lane&15][k=quad*8+j], k = ks*32 + q*8 + j  (verified rounds 2-3)
    bf16x8 ahi[2][4], alo[2][4];
#pragma unroll
    for (int s = 0; s < 2; ++s) {
#pragma unroll
        for (int ks = 0; ks < 4; ++ks) {
            const float* xp = x + (row0 + w * 32 + s * 16 + n) * DIM + ks * 32 + q * 8;
            float4 a0 = *(const float4*)xp;
            float4 a1 = *(const float4*)(xp + 4);
            float f[8] = {a0.x, a0.y, a0.z, a0.w, a1.x, a1.y, a1.z, a1.w};
            bf16x8 h8, l8;
#pragma unroll
            for (int j = 0; j < 8; ++j) {
                float bk, dd;
                h8[j] = (short)f2bf(f[j], &bk);
                l8[j] = (short)f2bf(f[j] - bk, &dd);
            }
            ahi[s][ks] = h8; alo[s][ks] = l8;
        }
    }

    float best[2][4], sec[2][4];
    int bidx[2][4];
#pragma unroll
    for (int s = 0; s < 2; ++s)
#pragma unroll
        for (int r = 0; r < 4; ++r) { best[s][r] = -3.4e38f; sec[s][r] = -3.4e38f; bidx[s][r] = 0; }

    // B stream: per-lane base for fragment B[k=ks*32+q*8+j][code=tile*16+n]
    // offsets in SHORTS: tile -> tile*16*DIM (=2048), ks -> ks*32  (ks*64 in round 4 was the bug)
    const unsigned short* bh_base = Ehi + n * DIM + q * 8;
    const unsigned short* bl_base = Elo + n * DIM + q * 8;

    auto tile_step = [&](int t, const bf16x8 (&bh)[4], const bf16x8 (&bl)[4]) {
        f32x4 acc0 = {0.f, 0.f, 0.f, 0.f};
        f32x4 acc1 = {0.f, 0.f, 0.f, 0.f};
#pragma unroll
        for (int ks = 0; ks < 4; ++ks) {
            acc0 = __builtin_amdgcn_mfma_f32_16x16x32_bf16(ahi[0][ks], bh[ks], acc0, 0, 0, 0);
            acc1 = __builtin_amdgcn_mfma_f32_16x16x32_bf16(ahi[1][ks], bh[ks], acc1, 0, 0, 0);
            acc0 = __builtin_amdgcn_mfma_f32_16x16x32_bf16(alo[0][ks], bh[ks], acc0, 0, 0, 0);
            acc1 = __builtin_amdgcn_mfma_f32_16x16x32_bf16(alo[1][ks], bh[ks], acc1, 0, 0, 0);
            acc0 = __builtin_amdgcn_mfma_f32_16x16x32_bf16(ahi[0][ks], bl[ks], acc0, 0, 0, 0);
            acc1 = __builtin_amdgcn_mfma_f32_16x16x32_bf16(ahi[1][ks], bl[ks], acc1, 0, 0, 0);
        }
        int code = t * 16 + n;
        float en = enorm[code];
#pragma unroll
        for (int rg = 0; rg < 4; ++rg) {
            float sc0 = fmaf(2.f, acc0[rg], -en);
            if (sc0 > best[0][rg]) { sec[0][rg] = best[0][rg]; best[0][rg] = sc0; bidx[0][rg] = code; }
            else if (sc0 > sec[0][rg]) sec[0][rg] = sc0;
            float sc1 = fmaf(2.f, acc1[rg], -en);
            if (sc1 > best[1][rg]) { sec[1][rg] = best[1][rg]; best[1][rg] = sc1; bidx[1][rg] = code; }
            else if (sc1 > sec[1][rg]) sec[1][rg] = sc1;
        }
    };

    bf16x8 b0h[4], b0l[4], b1h[4], b1l[4];
#pragma unroll
    for (int ks = 0; ks < 4; ++ks) {
        b0h[ks] = *(const bf16x8*)(bh_base + ks * 32);
        b0l[ks] = *(const bf16x8*)(bl_base + ks * 32);
    }

    for (int nt = 0; nt < KCODES / 16; nt += 2) {
        // prefetch tile nt+1 while computing tile nt (loads stay in flight — no barrier)
        {
            const unsigned short* ph = bh_base + (size_t)(nt + 1) * 2048;
            const unsigned short* pl = bl_base + (size_t)(nt + 1) * 2048;
#pragma unroll
            for (int ks = 0; ks < 4; ++ks) {
                b1h[ks] = *(const bf16x8*)(ph + ks * 32);
                b1l[ks] = *(const bf16x8*)(pl + ks * 32);
            }
        }
        tile_step(nt, b0h, b0l);
        {
            int ntn = (nt + 2) & 63;   // wrap: last prefetch reads tile 0 harmlessly
            const unsigned short* ph = bh_base + (size_t)ntn * 2048;
            const unsigned short* pl = bl_base + (size_t)ntn * 2048;
#pragma unroll
            for (int ks = 0; ks < 4; ++ks) {
                b0h[ks] = *(const bf16x8*)(ph + ks * 32);
                b0l[ks] = *(const bf16x8*)(pl + ks * 32);
            }
        }
        tile_step(nt + 1, b1h, b1l);
    }

    // reduce top-2 across the 16 col-classes (lanes differing in bits 0..3)
#pragma unroll
    for (int mask = 1; mask < 16; mask <<= 1) {
#pragma unroll
        for (int s = 0; s < 2; ++s)
#pragma unroll
            for (int rg = 0; rg < 4; ++rg) {
                float ob = __shfl_xor(best[s][rg], mask);
                float os = __shfl_xor(sec[s][rg], mask);
                int   oi = __shfl_xor(bidx[s][rg], mask);
                if (ob > best[s][rg] || (ob == best[s][rg] && oi < bidx[s][rg])) {
                    sec[s][rg] = fmaxf(best[s][rg], os);
                    best[s][rg] = ob; bidx[s][rg] = oi;
                } else {
                    sec[s][rg] = fmaxf(sec[s][rg], ob);
                }
            }
    }
    if (n == 0) {
#pragma unroll
        for (int s = 0; s < 2; ++s)
#pragma unroll
            for (int rg = 0; rg < 4; ++rg) {
                int r = w * 32 + s * 16 + q * 4 + rg;
                idx_l[r] = bidx[s][rg];
                if (best[s][rg] - sec[s][rg] < TAU) {
                    int p = atomicAdd(&fcnt, 1);
                    flist[p] = r;
                }
            }
    }
    __syncthreads();

    // exact fp32 refine for near-tie rows (same arithmetic as the round-1 all-fp32 kernel)
    int nf = fcnt;
    for (int f = w; f < nf; f += 4) {
        int r = flist[f];
        const float4* xg4 = (const float4*)(x + (row0 + r) * DIM);
        float b = -3.4e38f; int bi = 0;
        for (int c = lane * 16; c < lane * 16 + 16; ++c) {
            const float4* eg4 = (const float4*)(embed + (size_t)c * DIM);
            float s = 0.f;
#pragma unroll 8
            for (int d = 0; d < DIM / 4; ++d) {
                float4 xv = xg4[d], ev = eg4[d];
                s = fmaf(xv.x, ev.x, s); s = fmaf(xv.y, ev.y, s);
                s = fmaf(xv.z, ev.z, s); s = fmaf(xv.w, ev.w, s);
            }
            float sc = fmaf(2.f, s, -enorm[c]);
            if (sc > b) { b = sc; bi = c; }
        }
#pragma unroll
        for (int mask = 1; mask < 64; mask <<= 1) {
            float ob = __shfl_xor(b, mask);
            int   oi = __shfl_xor(bi, mask);
            if (ob > b || (ob == b && oi < bi)) { b = ob; bi = oi; }
        }
        if (lane == 0) idx_l[r] = bi;
    }
    __syncthreads();

    // fused gather (embed is L2-resident) + float index write
    const float4* e4 = (const float4*)embed;
    float4* oq4 = (float4*)outq + row0 * (DIM / 4);
#pragma unroll
    for (int i = 0; i < 16; ++i) {
        int g = tid + i * 256;
        int r = g >> 5, d4 = g & 31;
        int id = idx_l[r];
        oq4[g] = e4[(size_t)id * (DIM / 4) + d4];
    }
    if (tid < BROWS) outi[row0 + tid] = (float)idx_l[tid];
}

extern "C" void kernel_launch(void* const* d_in, const int* in_sizes, int n_in,
                              void* d_out, int out_size, void* d_ws, size_t ws_size,
                              hipStream_t stream) {
    const float* x     = (const float*)d_in[0];
    const float* embed = (const float*)d_in[1];
    const int x_elems  = in_sizes[0];          // 12,288,000
    const int n_rows   = x_elems / DIM;        // 96,000

    float*          enorm = (float*)d_ws;                                   // 4 KB
    unsigned short* Ehi   = (unsigned short*)((char*)d_ws + 4096);          // 256 KB
    unsigned short* Elo   = Ehi + (size_t)KCODES * DIM;                     // 256 KB

    float* outq = (float*)d_out;
    float* outi = (float*)d_out + (size_t)x_elems;

    pack_kernel<<<KCODES * 16 / 256, 256, 0, stream>>>(embed, Ehi, Elo, enorm);
    argmax_mfma_kernel<<<n_rows / BROWS, 256, 0, stream>>>(x, embed, Ehi, Elo, enorm, outq, outi);
}